// Round 3
// baseline (260.839 us; speedup 1.0000x reference)
//
#include <hip/hip_runtime.h>
#include <math.h>

typedef int intx4 __attribute__((ext_vector_type(4)));
typedef int intx8 __attribute__((ext_vector_type(8)));
typedef float floatx16 __attribute__((ext_vector_type(16)));

#define N_ROWS 8192
#define KDIM 1024

// E8M0 scale bytes: 123 -> 2^-4 per side (data pre-scaled by 2^4 each side)
#define SCALE_WORD 0x7B7B7B7B

// order-preserving float->int encoding for atomicMax
__device__ __forceinline__ int fenc(float f) {
  int i = __float_as_int(f);
  return i >= 0 ? i : (i ^ 0x7fffffff);
}
__device__ __forceinline__ float fdec(int e) {
  int b = e >= 0 ? e : (e ^ 0x7fffffff);
  return __int_as_float(b);
}

// async 16B global->LDS DMA (m97 pattern: per-lane global src, LDS dest must
// equal wave-uniform base + lane*16 -- ours does by construction).
__device__ __forceinline__ void gld_lds16(const void* g, void* l) {
  __builtin_amdgcn_global_load_lds(
      (const __attribute__((address_space(1))) unsigned int*)g,
      (__attribute__((address_space(3))) unsigned int*)l, 16, 0, 0);
}

// One WAVE per row (4 rows/block, no __syncthreads): computes 1/||x|| (fp32),
// writes row normalized*16 as e4m3 via HW cvt, inits the max slot.
__global__ __launch_bounds__(256) void normalize_kernel(
    const float* __restrict__ ex, const float* __restrict__ ey,
    unsigned char* __restrict__ exn, unsigned char* __restrict__ eyn,
    int* __restrict__ rowmax, int* __restrict__ colmax) {
  const int wave = threadIdx.x >> 6, lane = threadIdx.x & 63;
  const int gr = blockIdx.x * 4 + wave;  // 0..16383
  const float* x;
  unsigned char* out;
  int* mslot;
  int row;
  if (gr < N_ROWS) {
    x = ex; out = exn; mslot = rowmax; row = gr;
  } else {
    x = ey; out = eyn; mslot = colmax; row = gr - N_ROWS;
  }
  const float4* xr = (const float4*)(x + (size_t)row * KDIM);
  float4 v[4];
  float ss = 0.f;
#pragma unroll
  for (int j = 0; j < 4; ++j) {
    v[j] = xr[lane + j * 64];  // coalesced
    ss += v[j].x * v[j].x + v[j].y * v[j].y + v[j].z * v[j].z + v[j].w * v[j].w;
  }
#pragma unroll
  for (int off = 32; off > 0; off >>= 1) ss += __shfl_xor(ss, off, 64);
  const float rs = 16.0f * rsqrtf(fmaxf(ss, 1e-24f));  // 2^4 pre-scale
  int* op = (int*)(out + (size_t)row * KDIM);
#pragma unroll
  for (int j = 0; j < 4; ++j) {
    int w = __builtin_amdgcn_cvt_pk_fp8_f32(v[j].x * rs, v[j].y * rs, 0, false);
    w = __builtin_amdgcn_cvt_pk_fp8_f32(v[j].z * rs, v[j].w * rs, w, true);
    op[lane + j * 64] = w;
  }
  if (lane == 0) mslot[row] = (int)0x80000000;  // encoded -inf floor
}

// 128x128 tile GEMM (A @ B^T, row-major K-contiguous e4m3) using MX-scaled
// mfma_scale_f32_32x32x64_f8f6f4, fused with row/col max reduction.
//
// Round-14 = Round-13 resubmitted (round-13 bench died to a container/infra
// failure with no profile; design audit found no fault/hang vector: DMA
// pattern matches m97 exactly, all addresses in-bounds, barriers drain
// vmcnt before consumption).
//
// Round-13 change: fix r12's latency placement. r12 (A direct global->reg,
// consumed same step) put an L2 round-trip on every step's critical path:
// MfmaUtil 25->15.8, dur 119->178 us, even though LDS conflicts halved and
// FETCH_SIZE showed A was cache-absorbed. Two coupled fixes:
//  1) A prefetched ONE STEP AHEAD into a second reg set (A0/A1 ping-pong,
//     manual 2-unroll so every index is compile-time). The load for s+1
//     issues before COMPUTE(s); the barrier's vmcnt drain lands after a
//     full compute phase, so latency is hidden (r11-style), while LDS
//     still carries no A traffic.
//  2) B staging via __builtin_amdgcn_global_load_lds width=16. Our B path
//     was already the exact compatible pattern (pre-swizzled per-lane
//     global source + linear base+lane*16 LDS dest). Frees pf (8 VGPRs ->
//     budget for the doubled aF), deletes WRITEB + its vmcnt dependence,
//     and removes all ds_writes from the LDS pipe (16 ds_read_b128/step
//     remain + DMA).
// Reg budget at (256,4): ~47 arch VGPR + 64 acc = ~111 <= 128.
// Spill tripwire: WRITE_SIZE (clean ~20 MB; true spill was ~1 GB).
//
// LDS swizzle for B (verified r8): 64-B rows, 16-B chunk c of row r at
// slot c ^ ((r>>1)&3); staging pre-swizzles the global source chunk so
// the linear lane*16 dest lands swizzle-stored; fragment reads recover
// true chunk 2h+j -> operand bytes at (half,j,b) equal global
// k = k0+(2h+j)*16+b for BOTH A and B -> exact dot-product pairing
// (absmax 0.0 through r12).
__global__ __launch_bounds__(256, 4) void gemm_max_kernel(
    const unsigned char* __restrict__ A, const unsigned char* __restrict__ B,
    int* __restrict__ rowmax, int* __restrict__ colmax) {
  constexpr int TM = 128, BK = 64, K = KDIM;
  constexpr int BUF = TM * BK;                          // 8 KB per buffer
  __shared__ __align__(16) unsigned char sB[2 * BUF];   // 16 KB (B only)

  const int bm = blockIdx.x, bn = blockIdx.y;
  const int tid = threadIdx.x;
  const int lane = tid & 63, wave = tid >> 6;
  const int wm = wave >> 1, wn = wave & 1;  // 2x2 waves of 64x64
  const int l32 = lane & 31, half = lane >> 5;
  const int fsw = (l32 >> 1) & 3;                 // f(row) = (row>>1)&3
  const int oLo = (((2 * half + 0) ^ fsw) << 4);  // swizzled slot offsets
  const int oHi = (((2 * half + 1) ^ fsw) << 4);

  const char* Bb = (const char*)(B + (size_t)bn * TM * K);

  // A direct: per-lane base at (row = bm*128 + wm*64 + l32, col = half*32).
  // Per fragment, mi adds 32 rows; per step, k0 advances 64 bytes.
  const char* gAf =
      (const char*)A + (size_t)(bm * TM + wm * 64 + l32) * K + half * 32;

  typedef union {
    intx8 v8;
    intx4 v4[2];
  } frag8;

  floatx16 acc[2][2] = {};
  frag8 A0[2], A1[2];  // ping-pong A fragment sets (32 VGPRs)

  // B staging: wave w stages rows w*32..+31 per step (2 DMAs/lane).
  // Dest (linear lane*16): row r_d = wave*32 + (lane>>2), slot lane&3.
  // Source chunk = (lane&3) ^ f(r_d); +16-row second DMA keeps same offset.
  const int src_c16 = (((lane & 3) ^ ((lane >> 3) & 3)) << 4);
  const char* gB = Bb + (size_t)(wave * 32 + (lane >> 2)) * K + src_c16;
  unsigned char* wBl = sB + wave * 2048 + lane * 16;  // linear per-lane dest

#define GLB(k0, buf)                                                  \
  do {                                                                \
    gld_lds16(gB + (size_t)(k0), wBl + (buf)*BUF);                    \
    gld_lds16(gB + (size_t)(k0) + 16 * (size_t)K, wBl + (buf)*BUF + 1024); \
  } while (0)

#define LOADA(AF, k0)                                                        \
  do {                                                                       \
    AF[0].v4[0] = *(const intx4*)(gAf + (size_t)(k0));                       \
    AF[0].v4[1] = *(const intx4*)(gAf + (size_t)(k0) + 16);                  \
    AF[1].v4[0] = *(const intx4*)(gAf + (size_t)(k0) + 32 * (size_t)K);      \
    AF[1].v4[1] = *(const intx4*)(gAf + (size_t)(k0) + 32 * (size_t)K + 16); \
  } while (0)

#define COMPUTE(cur, AF)                                                    \
  do {                                                                      \
    _Pragma("unroll") for (int ni = 0; ni < 2; ++ni) {                      \
      const unsigned char* bBase =                                          \
          &sB[(cur)*BUF + (wn * 64 + ni * 32 + l32) * BK];                  \
      frag8 bF;                                                             \
      bF.v4[0] = *(const intx4*)(bBase + oLo);                              \
      bF.v4[1] = *(const intx4*)(bBase + oHi);                              \
      _Pragma("unroll") for (int mi = 0; mi < 2; ++mi)                      \
          acc[mi][ni] = __builtin_amdgcn_mfma_scale_f32_32x32x64_f8f6f4(    \
              AF[mi].v8, bF.v8, acc[mi][ni], 0, 0, 0, SCALE_WORD, 0,        \
              SCALE_WORD);                                                  \
    }                                                                       \
  } while (0)

  // Prologue: DMA buf0, prefetch A for step 0; barrier drains vmcnt.
  GLB(0, 0);
  LOADA(A0, 0);
  __syncthreads();

  // Steady state: DMA + A-prefetch for s+1 issue BEFORE COMPUTE(s), so
  // their latency hides under the MFMA phase; the end-of-step barrier
  // (with its vmcnt drain) is the only wait. Manual 2-unroll keeps the
  // A0/A1 and buffer indices compile-time (no scratch, rule #20).
#pragma unroll 1
  for (int s = 0; s < 14; s += 2) {
    GLB((size_t)(s + 1) * BK, 1);
    LOADA(A1, (size_t)(s + 1) * BK);
    COMPUTE(0, A0);
    __syncthreads();
    GLB((size_t)(s + 2) * BK, 0);
    LOADA(A0, (size_t)(s + 2) * BK);
    COMPUTE(1, A1);
    __syncthreads();
  }
  // s = 14:
  GLB((size_t)15 * BK, 1);
  LOADA(A1, (size_t)15 * BK);
  COMPUTE(0, A0);
  __syncthreads();
  // s = 15 (epilogue, no prefetch):
  COMPUTE(1, A1);

#undef GLB
#undef LOADA
#undef COMPUTE

  // 32x32 C/D layout (m74/m101, dtype-independent):
  //   col = lane&31, row = (reg&3) + 8*(reg>>2) + 4*(lane>>5), reg in [0,16)
  // Row maxes: in-lane over ni, shuffle across 32 cols (masks 1..16 stay
  // within a half), l32==0 lanes write.
#pragma unroll
  for (int mi = 0; mi < 2; ++mi) {
#pragma unroll
    for (int reg = 0; reg < 16; ++reg) {
      float v = fmaxf(acc[mi][0][reg], acc[mi][1][reg]);
#pragma unroll
      for (int m = 1; m < 32; m <<= 1) v = fmaxf(v, __shfl_xor(v, m, 64));
      if (l32 == 0) {
        const int grow = bm * TM + wm * 64 + mi * 32 +
                         (reg & 3) + 8 * (reg >> 2) + 4 * half;
        atomicMax(&rowmax[grow], fenc(v));
      }
    }
  }
  // Col maxes: in-lane over mi,reg (32 vals), combine halves via xor 32.
#pragma unroll
  for (int ni = 0; ni < 2; ++ni) {
    float v = -3.402823466e38f;
#pragma unroll
    for (int mi = 0; mi < 2; ++mi)
#pragma unroll
      for (int reg = 0; reg < 16; ++reg) v = fmaxf(v, acc[mi][ni][reg]);
    v = fmaxf(v, __shfl_xor(v, 32, 64));
    if (half == 0) {
      const int gcol = bn * TM + wn * 64 + ni * 32 + l32;
      atomicMax(&colmax[gcol], fenc(v));
    }
  }
}

__global__ __launch_bounds__(1024) void finalize_kernel(
    const int* __restrict__ rowmax, const int* __restrict__ colmax,
    float* __restrict__ out) {
  const int tid = threadIdx.x;
  float s1 = 0.f, s2 = 0.f;
  for (int i = tid; i < N_ROWS; i += 1024) {
    s1 += 1.0f - fdec(rowmax[i]);
    s2 += 1.0f - fdec(colmax[i]);
  }
#pragma unroll
  for (int off = 32; off > 0; off >>= 1) {
    s1 += __shfl_down(s1, off, 64);
    s2 += __shfl_down(s2, off, 64);
  }
  __shared__ float r1[16], r2[16];
  if ((tid & 63) == 0) {
    r1[tid >> 6] = s1;
    r2[tid >> 6] = s2;
  }
  __syncthreads();
  if (tid == 0) {
    const double SIGMA = 0.3;
    const double H_CONST = 0.5 * log(2.0 * 3.14159265358979323846 * SIGMA * SIGMA) + 0.5;
    const float HS = (float)(H_CONST / SIGMA);
    float a1 = 0.f, a2 = 0.f;
#pragma unroll
    for (int w = 0; w < 16; ++w) {
      a1 += r1[w];
      a2 += r2[w];
    }
    out[0] = HS * a1;
    out[1] = HS * a2;
  }
}

extern "C" void kernel_launch(void* const* d_in, const int* in_sizes, int n_in,
                              void* d_out, int out_size, void* d_ws, size_t ws_size,
                              hipStream_t stream) {
  const float* ex = (const float*)d_in[0];
  const float* ey = (const float*)d_in[1];
  float* out = (float*)d_out;
  char* ws = (char*)d_ws;

  unsigned char* exn = (unsigned char*)ws;                                   // 8 MB
  unsigned char* eyn = (unsigned char*)(ws + (size_t)N_ROWS * KDIM);         // 8 MB
  int* rowmax = (int*)(ws + (size_t)N_ROWS * KDIM * 2);                      // 32 KB
  int* colmax = rowmax + N_ROWS;                                             // 32 KB

  normalize_kernel<<<2 * N_ROWS / 4, 256, 0, stream>>>(ex, ey, exn, eyn, rowmax, colmax);
  gemm_max_kernel<<<dim3(64, 64), 256, 0, stream>>>(exn, eyn, rowmax, colmax);
  finalize_kernel<<<1, 1024, 0, stream>>>(rowmax, colmax, out);
}

// Round 4
// 201.246 us; speedup vs baseline: 1.2961x; 1.2961x over previous
//
#include <hip/hip_runtime.h>
#include <math.h>

typedef int intx4 __attribute__((ext_vector_type(4)));
typedef int intx8 __attribute__((ext_vector_type(8)));
typedef float floatx16 __attribute__((ext_vector_type(16)));

#define N_ROWS 8192
#define KDIM 1024

// E8M0 scale bytes: 123 -> 2^-4 per side (data pre-scaled by 2^4 each side)
#define SCALE_WORD 0x7B7B7B7B

// order-preserving float->int encoding for atomicMax
__device__ __forceinline__ int fenc(float f) {
  int i = __float_as_int(f);
  return i >= 0 ? i : (i ^ 0x7fffffff);
}
__device__ __forceinline__ float fdec(int e) {
  int b = e >= 0 ? e : (e ^ 0x7fffffff);
  return __int_as_float(b);
}

// async 16B global->LDS DMA (m97 pattern: per-lane global src, LDS dest must
// equal wave-uniform base + lane*16 -- ours does by construction).
__device__ __forceinline__ void gld_lds16(const void* g, void* l) {
  __builtin_amdgcn_global_load_lds(
      (const __attribute__((address_space(1))) unsigned int*)g,
      (__attribute__((address_space(3))) unsigned int*)l, 16, 0, 0);
}

// One WAVE per row (4 rows/block, no __syncthreads): computes 1/||x|| (fp32),
// writes row normalized*16 as e4m3 via HW cvt, inits the max slot.
__global__ __launch_bounds__(256) void normalize_kernel(
    const float* __restrict__ ex, const float* __restrict__ ey,
    unsigned char* __restrict__ exn, unsigned char* __restrict__ eyn,
    int* __restrict__ rowmax, int* __restrict__ colmax) {
  const int wave = threadIdx.x >> 6, lane = threadIdx.x & 63;
  const int gr = blockIdx.x * 4 + wave;  // 0..16383
  const float* x;
  unsigned char* out;
  int* mslot;
  int row;
  if (gr < N_ROWS) {
    x = ex; out = exn; mslot = rowmax; row = gr;
  } else {
    x = ey; out = eyn; mslot = colmax; row = gr - N_ROWS;
  }
  const float4* xr = (const float4*)(x + (size_t)row * KDIM);
  float4 v[4];
  float ss = 0.f;
#pragma unroll
  for (int j = 0; j < 4; ++j) {
    v[j] = xr[lane + j * 64];  // coalesced
    ss += v[j].x * v[j].x + v[j].y * v[j].y + v[j].z * v[j].z + v[j].w * v[j].w;
  }
#pragma unroll
  for (int off = 32; off > 0; off >>= 1) ss += __shfl_xor(ss, off, 64);
  const float rs = 16.0f * rsqrtf(fmaxf(ss, 1e-24f));  // 2^4 pre-scale
  int* op = (int*)(out + (size_t)row * KDIM);
#pragma unroll
  for (int j = 0; j < 4; ++j) {
    int w = __builtin_amdgcn_cvt_pk_fp8_f32(v[j].x * rs, v[j].y * rs, 0, false);
    w = __builtin_amdgcn_cvt_pk_fp8_f32(v[j].z * rs, v[j].w * rs, w, true);
    op[lane + j * 64] = w;
  }
  if (lane == 0) mslot[row] = (int)0x80000000;  // encoded -inf floor
}

// 128x128 tile GEMM (A @ B^T, row-major K-contiguous e4m3) using MX-scaled
// mfma_scale_f32_32x32x64_f8f6f4, fused with row/col max reduction.
//
// Round-15 change: r11 structure + global_load_lds DMA staging for BOTH A
// and B. Post-mortem of r13/r14: WRITE_SIZE 20->48 MB + FETCH +8 MB =
// scratch spill. (256,4) caps total regs at 128; acc=64 AGPR leaves 64
// arch VGPRs, and the A0/A1 ping-pong (32 VGPRs) pushed past the cap ->
// spilled fragments -> L2 round-trip inside COMPUTE -> step-window 4464 ->
// 6594 cyc despite lower pipe demand. Also recalibrated: MFMA floor is
// 27 us (1.05M wave-MFMAs x 64 cyc); MfmaUtil derived counter is accurate
// (23% @ r11). r11's binding pipe was LDS (48 b128 ops/block-step, ~63%
// busy, wall 1.6x demand). Conflicts (4.19M) are read-side only: removing
// all ds_writes in r13 left the count bit-identical.
//
// So: keep A in LDS (no reg pressure), but stage it with DMA. Staging was
// already the DMA-compatible pattern (pre-swizzled per-lane global src +
// linear base+lane*16 dest), so identical bytes land in identical slots;
// COMPUTE and swizzle recovery unchanged -> absmax 0.0 preserved. This
// removes 16 ds_write_b128/block-step (48 -> 32 LDS wave-ops), deletes the
// WRITET vmcnt dependence, and frees the 16 pf VGPRs (reg demand drops
// BELOW r11 -> no spill at (256,4)).
// Tripwires: WRITE_SIZE back to ~20 MB, VGPR_Count <= 64.
//
// LDS swizzle (verified r8): 64-B rows, 16-B chunk c of row r at slot
// c ^ ((r>>1)&3); staging pre-swizzles the global source chunk so the
// linear lane*16 dest lands swizzle-stored; fragment reads recover true
// chunk 2h+j -> operand bytes at (half,j,b) equal global k=k0+(2h+j)*16+b
// for BOTH A and B -> exact dot-product pairing (absmax 0.0 thru r14).
__global__ __launch_bounds__(256, 4) void gemm_max_kernel(
    const unsigned char* __restrict__ A, const unsigned char* __restrict__ B,
    int* __restrict__ rowmax, int* __restrict__ colmax) {
  constexpr int TM = 128, BK = 64, K = KDIM;
  constexpr int BUF = TM * BK;                          // 8 KB per buffer
  __shared__ __align__(16) unsigned char sA[2 * BUF];   // 16 KB
  __shared__ __align__(16) unsigned char sB[2 * BUF];   // 16 KB

  const int bm = blockIdx.x, bn = blockIdx.y;
  const int tid = threadIdx.x;
  const int lane = tid & 63, wave = tid >> 6;
  const int wm = wave >> 1, wn = wave & 1;  // 2x2 waves of 64x64
  const int l32 = lane & 31, half = lane >> 5;
  const int fsw = (l32 >> 1) & 3;                 // f(row) = (row>>1)&3
  const int oLo = (((2 * half + 0) ^ fsw) << 4);  // swizzled slot offsets
  const int oHi = (((2 * half + 1) ^ fsw) << 4);

  const char* Ab = (const char*)(A + (size_t)bm * TM * K);
  const char* Bb = (const char*)(B + (size_t)bn * TM * K);

  floatx16 acc[2][2] = {};

  // Staging: wave w stages rows w*32..+31 of each tile per step (2 DMAs
  // per array per lane). Dest (linear lane*16): row r_d = wave*32 +
  // (lane>>2), slot lane&3. Source chunk = (lane&3) ^ f(r_d); the +16-row
  // second DMA keeps the same offset (f(r+16)==f(r)).
  const int src_c16 = (((lane & 3) ^ ((lane >> 3) & 3)) << 4);
  const char* gA = Ab + (size_t)(wave * 32 + (lane >> 2)) * K + src_c16;
  const char* gB = Bb + (size_t)(wave * 32 + (lane >> 2)) * K + src_c16;
  unsigned char* wA = sA + wave * 2048 + lane * 16;  // linear per-lane dest
  unsigned char* wB = sB + wave * 2048 + lane * 16;

#define STAGE(k0, buf)                                                     \
  do {                                                                     \
    gld_lds16(gA + (size_t)(k0), wA + (buf)*BUF);                          \
    gld_lds16(gA + (size_t)(k0) + 16 * (size_t)K, wA + (buf)*BUF + 1024);  \
    gld_lds16(gB + (size_t)(k0), wB + (buf)*BUF);                          \
    gld_lds16(gB + (size_t)(k0) + 16 * (size_t)K, wB + (buf)*BUF + 1024);  \
  } while (0)

#define COMPUTE(cur)                                                        \
  do {                                                                      \
    intx8 aF[2];                                                            \
    _Pragma("unroll") for (int mi = 0; mi < 2; ++mi) {                      \
      const unsigned char* aBase =                                          \
          &sA[(cur)*BUF + (wm * 64 + mi * 32 + l32) * BK];                  \
      const intx4 lo = *(const intx4*)(aBase + oLo);                        \
      const intx4 hi = *(const intx4*)(aBase + oHi);                        \
      aF[mi] = __builtin_shufflevector(lo, hi, 0, 1, 2, 3, 4, 5, 6, 7);     \
    }                                                                       \
    _Pragma("unroll") for (int ni = 0; ni < 2; ++ni) {                      \
      const unsigned char* bBase =                                          \
          &sB[(cur)*BUF + (wn * 64 + ni * 32 + l32) * BK];                  \
      const intx4 lo = *(const intx4*)(bBase + oLo);                        \
      const intx4 hi = *(const intx4*)(bBase + oHi);                        \
      const intx8 bF =                                                      \
          __builtin_shufflevector(lo, hi, 0, 1, 2, 3, 4, 5, 6, 7);          \
      _Pragma("unroll") for (int mi = 0; mi < 2; ++mi)                      \
          acc[mi][ni] = __builtin_amdgcn_mfma_scale_f32_32x32x64_f8f6f4(    \
              aF[mi], bF, acc[mi][ni], 0, 0, 0, SCALE_WORD, 0,              \
              SCALE_WORD);                                                  \
    }                                                                       \
  } while (0)

  // Prologue: DMA buf0; barrier drains vmcnt(0) -> tile 0 resident.
  STAGE(0, 0);
  __syncthreads();

  // Steady state: DMA for s+1 (other buffer) issues BEFORE COMPUTE(s);
  // its latency hides under the MFMA phase; the single end-of-step
  // barrier (vmcnt drain) makes it resident for the next step. One
  // barrier per step; no WRITET data dependence anymore.
#pragma unroll 1
  for (int step = 0; step < K / BK - 1; ++step) {
    STAGE((size_t)(step + 1) * BK, (step + 1) & 1);
    COMPUTE(step & 1);
    __syncthreads();
  }
  COMPUTE((K / BK - 1) & 1);

#undef STAGE
#undef COMPUTE

  // 32x32 C/D layout (m74/m101, dtype-independent):
  //   col = lane&31, row = (reg&3) + 8*(reg>>2) + 4*(lane>>5), reg in [0,16)
  // Row maxes: in-lane over ni, shuffle across 32 cols (masks 1..16 stay
  // within a half), l32==0 lanes write.
#pragma unroll
  for (int mi = 0; mi < 2; ++mi) {
#pragma unroll
    for (int reg = 0; reg < 16; ++reg) {
      float v = fmaxf(acc[mi][0][reg], acc[mi][1][reg]);
#pragma unroll
      for (int m = 1; m < 32; m <<= 1) v = fmaxf(v, __shfl_xor(v, m, 64));
      if (l32 == 0) {
        const int grow = bm * TM + wm * 64 + mi * 32 +
                         (reg & 3) + 8 * (reg >> 2) + 4 * half;
        atomicMax(&rowmax[grow], fenc(v));
      }
    }
  }
  // Col maxes: in-lane over mi,reg (32 vals), combine halves via xor 32.
#pragma unroll
  for (int ni = 0; ni < 2; ++ni) {
    float v = -3.402823466e38f;
#pragma unroll
    for (int mi = 0; mi < 2; ++mi)
#pragma unroll
      for (int reg = 0; reg < 16; ++reg) v = fmaxf(v, acc[mi][ni][reg]);
    v = fmaxf(v, __shfl_xor(v, 32, 64));
    if (half == 0) {
      const int gcol = bn * TM + wn * 64 + ni * 32 + l32;
      atomicMax(&colmax[gcol], fenc(v));
    }
  }
}

__global__ __launch_bounds__(1024) void finalize_kernel(
    const int* __restrict__ rowmax, const int* __restrict__ colmax,
    float* __restrict__ out) {
  const int tid = threadIdx.x;
  float s1 = 0.f, s2 = 0.f;
  for (int i = tid; i < N_ROWS; i += 1024) {
    s1 += 1.0f - fdec(rowmax[i]);
    s2 += 1.0f - fdec(colmax[i]);
  }
#pragma unroll
  for (int off = 32; off > 0; off >>= 1) {
    s1 += __shfl_down(s1, off, 64);
    s2 += __shfl_down(s2, off, 64);
  }
  __shared__ float r1[16], r2[16];
  if ((tid & 63) == 0) {
    r1[tid >> 6] = s1;
    r2[tid >> 6] = s2;
  }
  __syncthreads();
  if (tid == 0) {
    const double SIGMA = 0.3;
    const double H_CONST = 0.5 * log(2.0 * 3.14159265358979323846 * SIGMA * SIGMA) + 0.5;
    const float HS = (float)(H_CONST / SIGMA);
    float a1 = 0.f, a2 = 0.f;
#pragma unroll
    for (int w = 0; w < 16; ++w) {
      a1 += r1[w];
      a2 += r2[w];
    }
    out[0] = HS * a1;
    out[1] = HS * a2;
  }
}

extern "C" void kernel_launch(void* const* d_in, const int* in_sizes, int n_in,
                              void* d_out, int out_size, void* d_ws, size_t ws_size,
                              hipStream_t stream) {
  const float* ex = (const float*)d_in[0];
  const float* ey = (const float*)d_in[1];
  float* out = (float*)d_out;
  char* ws = (char*)d_ws;

  unsigned char* exn = (unsigned char*)ws;                                   // 8 MB
  unsigned char* eyn = (unsigned char*)(ws + (size_t)N_ROWS * KDIM);         // 8 MB
  int* rowmax = (int*)(ws + (size_t)N_ROWS * KDIM * 2);                      // 32 KB
  int* colmax = rowmax + N_ROWS;                                             // 32 KB

  normalize_kernel<<<2 * N_ROWS / 4, 256, 0, stream>>>(ex, ey, exn, eyn, rowmax, colmax);
  gemm_max_kernel<<<dim3(64, 64), 256, 0, stream>>>(exn, eyn, rowmax, colmax);
  finalize_kernel<<<1, 1024, 0, stream>>>(rowmax, colmax, out);
}